// Round 5
// baseline (142.547 us; speedup 1.0000x reference)
//
#include <hip/hip_runtime.h>
#include <math.h>

#define EDIM 100
#define KP   128          // padded K
#define NF   4000
#define NN   4000
#define NB   8
#define NP   4096         // padded N and F
#define BN   128          // n-rows per main block
#define BF   64           // f-cols per tile
#define NT   4            // f-tiles per main block
#define FCH  16           // f-chunks = NP/(BF*NT)
#define TRS  68           // transpose row stride (floats)

#define CVT_BLOCKS 1536   // 3 matrices * (NP*KP/4)/256
#define E2_BLOCKS  16
#define P_BLOCKS   128    // NP/32

typedef __attribute__((ext_vector_type(8))) short short8;
typedef __attribute__((ext_vector_type(4))) float floatx4;

// Static device scratch.
__device__ __align__(16) unsigned short g_A [NP * KP];   // ent  bf16
__device__ __align__(16) unsigned short g_B1[NP * KP];   // fa1  bf16
__device__ __align__(16) unsigned short g_B2[NP * KP];   // fa2  bf16
__device__ __align__(16) float g_P[2 * NB * NP];         // [g][b][f], +INF pad
__device__ float g_e2[NN];
__device__ float g_part[2 * NB * FCH * NP];              // [g][b][fch][n]

__device__ __forceinline__ unsigned short f2bf(float x) {
    union { float f; unsigned int u; } v; v.f = x;
    unsigned int r = v.u + 0x7FFFu + ((v.u >> 16) & 1u);  // RNE
    return (unsigned short)(r >> 16);
}

// Fused prep: convert (bf16 pad), e2, P — partitioned by blockIdx.x.
__global__ void __launch_bounds__(256) prep(const float* __restrict__ rel,
                                            const float* __restrict__ arg1,
                                            const float* __restrict__ arg2,
                                            const float* __restrict__ frel,
                                            const float* __restrict__ fa1,
                                            const float* __restrict__ fa2,
                                            const float* __restrict__ ent) {
    __shared__ float lf[3][32][104];   // fact rows (frel,fa1,fa2), padded
    __shared__ float lq[3][8][104];    // rel,arg1,arg2 rows
    const int bid = blockIdx.x;
    const int t = threadIdx.x;

    if (bid < CVT_BLOCKS) {
        // ---- convert fp32 [4000][100] -> bf16 [4096][128] zero-pad ----
        const int mat = bid >> 9;                  // /512
        const int g4 = ((bid & 511) * 256 + t);    // float4-chunk id, 131072/mat
        const int rw = g4 >> 5;                    // row
        const int ck = g4 & 31;                    // chunk-of-row (32 x 4 floats)
        const float* src = (mat == 0) ? ent : (mat == 1) ? fa1 : fa2;
        unsigned short* dst = (mat == 0) ? g_A : (mat == 1) ? g_B1 : g_B2;
        float4 v = {0.f, 0.f, 0.f, 0.f};
        if (rw < NF && ck < 25) v = ((const float4*)src)[rw * 25 + ck];
        ushort4 o;
        o.x = f2bf(v.x); o.y = f2bf(v.y); o.z = f2bf(v.z); o.w = f2bf(v.w);
        ((ushort4*)dst)[g4] = o;
        return;
    }
    if (bid < CVT_BLOCKS + E2_BLOCKS) {
        int n = (bid - CVT_BLOCKS) * 256 + t;
        if (n < NN) {
            const float4* ep = (const float4*)(ent + n * EDIM);
            float s = 0.f;
            #pragma unroll
            for (int i = 0; i < 25; i++) {
                float4 v = ep[i];
                s += v.x * v.x + v.y * v.y + v.z * v.z + v.w * v.w;
            }
            g_e2[n] = s;
        }
        return;
    }
    // ---- P part: 32 f's per block ----
    const int fb = bid - CVT_BLOCKS - E2_BLOCKS;   // 0..127
    // stage fact rows: 3 * 32 rows * 25 float4 = 2400
    for (int i = t; i < 2400; i += 256) {
        int mat = i / 800, rem = i % 800;
        int rr = rem / 25, kc = rem % 25;
        int gf = fb * 32 + rr;
        const float* src = (mat == 0) ? frel : (mat == 1) ? fa1 : fa2;
        float4 v = {0.f, 0.f, 0.f, 0.f};
        if (gf < NF) v = ((const float4*)src)[gf * 25 + kc];
        *(float4*)&lf[mat][rr][kc * 4] = v;
    }
    // stage rel/arg rows: 3 * 8 * 25 = 600
    for (int i = t; i < 600; i += 256) {
        int mat = i / 200, rem = i % 200;
        int rr = rem / 25, kc = rem % 25;
        const float* src = (mat == 0) ? rel : (mat == 1) ? arg1 : arg2;
        *(float4*)&lq[mat][rr][kc * 4] = ((const float4*)src)[rr * 25 + kc];
    }
    __syncthreads();
    const int fl = t >> 3, b = t & 7;
    const int f = fb * 32 + fl;
    float nf = 0.f, dr = 0.f, d1 = 0.f, d2 = 0.f, qr = 0.f, q1 = 0.f, q2 = 0.f;
    for (int kc = 0; kc < 25; kc++) {
        float4 vr = *(const float4*)&lf[0][fl][kc * 4];
        float4 v1 = *(const float4*)&lf[1][fl][kc * 4];
        float4 v2 = *(const float4*)&lf[2][fl][kc * 4];
        float4 rb = *(const float4*)&lq[0][b][kc * 4];
        float4 a1 = *(const float4*)&lq[1][b][kc * 4];
        float4 a2 = *(const float4*)&lq[2][b][kc * 4];
        nf += vr.x*vr.x + vr.y*vr.y + vr.z*vr.z + vr.w*vr.w
            + v1.x*v1.x + v1.y*v1.y + v1.z*v1.z + v1.w*v1.w
            + v2.x*v2.x + v2.y*v2.y + v2.z*v2.z + v2.w*v2.w;
        dr += vr.x*rb.x + vr.y*rb.y + vr.z*rb.z + vr.w*rb.w;
        d1 += v1.x*a1.x + v1.y*a1.y + v1.z*a1.z + v1.w*a1.w;
        d2 += v2.x*a2.x + v2.y*a2.y + v2.z*a2.z + v2.w*a2.w;
        qr += rb.x*rb.x + rb.y*rb.y + rb.z*rb.z + rb.w*rb.w;
        q1 += a1.x*a1.x + a1.y*a1.y + a1.z*a1.z + a1.w*a1.w;
        q2 += a2.x*a2.x + a2.y*a2.y + a2.z*a2.z + a2.w*a2.w;
    }
    float psp = nf + qr + q1 - 2.f * (dr + d1);
    float ppo = nf + qr + q2 - 2.f * (dr + d2);
    if (f >= NF) { psp = __builtin_inff(); ppo = __builtin_inff(); }
    g_P[(0 * NB + b) * NP + f] = psp;
    g_P[(1 * NB + b) * NP + f] = ppo;
}

// Main: block loops NT=4 f-tiles of 128n x 64f; bf16 MFMA 16x16x32;
// per-tile transpose epilogue folds running mins in registers.
__global__ void __launch_bounds__(256, 2) main_kernel() {
    __shared__ float4 smem4[4352];          // 69632 B
    float4* lA4  = smem4;                   // 32 KB
    float4* lB14 = smem4 + 2048;            // 16 KB
    float4* lB24 = smem4 + 3072;            // 16 KB
    float*  tr   = (float*)smem4;           // overlay: [2][128][TRS]

    const int t = threadIdx.x;
    const int n0 = blockIdx.x * BN;
    const int fch = blockIdx.y;

    const int lane = t & 63;
    const int c = lane & 15;
    const int q = lane >> 4;
    const int w = t >> 6;
    const int w32 = w * 32;
    const int g2 = t >> 7;                  // phase-2 role
    const int row = t & 127;

    float m[NB];
    #pragma unroll
    for (int b = 0; b < NB; b++) m[b] = __builtin_inff();

    const float4* gA4 = (const float4*)g_A;
    const float4* gB14 = (const float4*)g_B1;
    const float4* gB24 = (const float4*)g_B2;

    for (int it = 0; it < NT; it++) {
        const int f0 = (fch * NT + it) * BF;

        // ---- stage (A re-staged each tile; tr overlay clobbered it) ----
        #pragma unroll
        for (int i = 0; i < 8; i++) {
            int gc = i * 256 + t;
            int rw = gc >> 4, ch = gc & 15;
            lA4[rw * 16 + (ch ^ (rw & 15))] = gA4[n0 * 16 + gc];
        }
        #pragma unroll
        for (int i = 0; i < 4; i++) {
            int gc = i * 256 + t;
            int rw = gc >> 4, ch = gc & 15;
            int sl = rw * 16 + (ch ^ (rw & 15));
            lB14[sl] = gB14[f0 * 16 + gc];
            lB24[sl] = gB24[f0 * 16 + gc];
        }
        __syncthreads();

        // ---- MFMA ----
        const short8* pA  = (const short8*)lA4;
        const short8* pB1 = (const short8*)lB14;
        const short8* pB2 = (const short8*)lB24;
        floatx4 acc[2][2][4];
        #pragma unroll
        for (int g = 0; g < 2; g++)
            #pragma unroll
            for (int mt = 0; mt < 2; mt++)
                #pragma unroll
                for (int ft = 0; ft < 4; ft++)
                    acc[g][mt][ft] = (floatx4){0.f, 0.f, 0.f, 0.f};
        #pragma unroll
        for (int s = 0; s < 4; s++) {
            const int base = s * 4 + q;
            short8 a0 = pA[(w32 + c) * 16 + (base ^ c)];
            short8 a1 = pA[(w32 + 16 + c) * 16 + (base ^ c)];
            #pragma unroll
            for (int ft = 0; ft < 4; ft++) {
                int sl = (ft * 16 + c) * 16 + (base ^ c);
                short8 b1 = pB1[sl];
                short8 b2 = pB2[sl];
                acc[0][0][ft] = __builtin_amdgcn_mfma_f32_16x16x32_bf16(a0, b2, acc[0][0][ft], 0, 0, 0);
                acc[0][1][ft] = __builtin_amdgcn_mfma_f32_16x16x32_bf16(a1, b2, acc[0][1][ft], 0, 0, 0);
                acc[1][0][ft] = __builtin_amdgcn_mfma_f32_16x16x32_bf16(a0, b1, acc[1][0][ft], 0, 0, 0);
                acc[1][1][ft] = __builtin_amdgcn_mfma_f32_16x16x32_bf16(a1, b1, acc[1][1][ft], 0, 0, 0);
            }
        }
        __syncthreads();

        // ---- transpose G -> tr[g][row][f] (2 lanes/bank = free) ----
        #pragma unroll
        for (int g = 0; g < 2; g++)
            #pragma unroll
            for (int mt = 0; mt < 2; mt++)
                #pragma unroll
                for (int ft = 0; ft < 4; ft++)
                    #pragma unroll
                    for (int r = 0; r < 4; r++)
                        tr[(g * BN + w32 + mt * 16 + q * 4 + r) * TRS + ft * 16 + c] =
                            acc[g][mt][ft][r];
        __syncthreads();

        // ---- fold: thread owns (g,row); P via wave-uniform s_load ----
        const float4* trg = (const float4*)(tr + (g2 * BN + row) * TRS);
        float4 G4[16];
        #pragma unroll
        for (int ch = 0; ch < 16; ch++) G4[ch] = trg[ch];
        #pragma unroll
        for (int b = 0; b < NB; b++) {
            const float4* Pp = (const float4*)(g_P + (g2 * NB + b) * NP + f0);
            float4 m4 = {__builtin_inff(), __builtin_inff(), __builtin_inff(), __builtin_inff()};
            #pragma unroll
            for (int ch = 0; ch < 16; ch++) {
                float4 p = Pp[ch];
                m4.x = fminf(m4.x, fmaf(-2.f, G4[ch].x, p.x));
                m4.y = fminf(m4.y, fmaf(-2.f, G4[ch].y, p.y));
                m4.z = fminf(m4.z, fmaf(-2.f, G4[ch].z, p.z));
                m4.w = fminf(m4.w, fmaf(-2.f, G4[ch].w, p.w));
            }
            m[b] = fminf(m[b], fminf(fminf(m4.x, m4.y), fminf(m4.z, m4.w)));
        }
        __syncthreads();   // tr region re-staged next iter
    }

    #pragma unroll
    for (int b = 0; b < NB; b++)
        g_part[((g2 * NB + b) * FCH + fch) * NP + n0 + row] = m[b];
}

__global__ void finalize(float* __restrict__ out) {
    int idx = blockIdx.x * 256 + threadIdx.x;   // out layout (g*NB+b)*NN+n
    if (idx >= 2 * NB * NN) return;
    int sb = idx / NN;
    int n = idx % NN;
    float m = __builtin_inff();
    #pragma unroll
    for (int j = 0; j < FCH; j++) m = fminf(m, g_part[(sb * FCH + j) * NP + n]);
    float d2 = fmaxf(m + g_e2[n], 0.f);
    out[idx] = expf(-0.5f * d2);
}

extern "C" void kernel_launch(void* const* d_in, const int* in_sizes, int n_in,
                              void* d_out, int out_size, void* d_ws, size_t ws_size,
                              hipStream_t stream) {
    const float* rel  = (const float*)d_in[0];
    const float* arg1 = (const float*)d_in[1];
    const float* arg2 = (const float*)d_in[2];
    const float* frel = (const float*)d_in[3];
    const float* fa1  = (const float*)d_in[4];
    const float* fa2  = (const float*)d_in[5];
    const float* ent  = (const float*)d_in[6];
    float* out = (float*)d_out;

    prep<<<CVT_BLOCKS + E2_BLOCKS + P_BLOCKS, 256, 0, stream>>>(rel, arg1, arg2, frel, fa1, fa2, ent);
    main_kernel<<<dim3(NP / BN, FCH), 256, 0, stream>>>();
    finalize<<<(2 * NB * NN + 255) / 256, 256, 0, stream>>>(out);
}